// Round 7
// baseline (260.733 us; speedup 1.0000x reference)
//
#include <hip/hip_runtime.h>
#include <stdint.h>

// Problem constants
#define B_ 16
#define T_ 512
#define F_ 32
#define CI_ 128
#define CO_ 128
#define K_ 3
#define LPAD 4              // DIL*(K-1)
#define TM 64               // output rows per tile
#define XROWS (TM + LPAD)   // 68 staged x rows
#define XPITCH 136          // bf16/row: 128 data + 8 pad (272B)
#define NWCH 24             // W chunks: 3 taps * 8 kc (K=16 each)
#define WCH_ELEMS (CO_ * 16)  // 2048 elems per chunk
#define NXV 9               // ceil(68*32 / 256) float4 per thread

typedef __attribute__((ext_vector_type(8))) __bf16 bf16x8;
typedef __attribute__((ext_vector_type(16))) float f32x16;

__device__ __forceinline__ uint16_t f2bf(float x) {
  uint32_t u = __builtin_bit_cast(uint32_t, x);
  u += 0x7fffu + ((u >> 16) & 1u);
  return (uint16_t)(u >> 16);
}

// Coalesced repack: w[f][o][i][k] fp32 -> wt3[f][tap*8+kc][o][16] bf16
// (kc = i>>4 selects the K=16 window, inner idx = i&15).
__global__ __launch_bounds__(256) void repack_w(const float* __restrict__ w,
                                                uint16_t* __restrict__ wt3) {
  int idx = blockIdx.x * 256 + threadIdx.x; // (f*CO+o)*CI + i
  int i = idx & (CI_ - 1);
  int fo = idx >> 7;
  int o = fo & (CO_ - 1);
  int f = fo >> 7;
  const float* src = w + (size_t)idx * K_;
  float a0 = src[0], a1 = src[1], a2 = src[2];
  size_t base = ((size_t)(f * NWCH + (i >> 4)) * CO_ + o) * 16 + (i & 15);
  const size_t tapstride = (size_t)8 * CO_ * 16; // 16384
  wt3[base] = f2bf(a0);
  wt3[base + tapstride] = f2bf(a1);
  wt3[base + 2 * tapstride] = f2bf(a2);
}

// ===== 32x32x16 MFMA restructure (Config C) =====
// Block = (f, b), 512 blocks, 256 threads = 4 waves. Wave w owns co-group
// wco = w (32 co) and ALL 64 t-rows of the tile (2 x 32t acc chains).
// A = W (M=32 co): lane row = l&31, k = (l>>5)*8 + j; 24 frags x 4 VGPR = 96.
// B = x (N=32 t): lane col = l&31 -> t-row, same k split; 1 b128 LDS read
// feeds 32768 FLOP (2x the 16x16x32 ratio) -> DS reads/CU-phase halved.
// D: col = l&31 = t', row = (reg&3)+8*(reg>>2)+4*(l>>5) = o' -> reg quad g
// holds 4 consecutive co at 8g+4h -> float4 stores, as before.
// ~205 VGPR -> __launch_bounds__(256,2): 2 blocks/CU, 2 waves/SIMD, one from
// EACH block (anti-phased by stagger) -> cross-block latency overlap.
// Counted barrier (R5) + stagger (R6, +8%) retained.
template <bool PACKED>
__global__ __launch_bounds__(256, 2) void conv_main(
    const float* __restrict__ x, const uint16_t* __restrict__ wt3,
    const float* __restrict__ wraw, const float* __restrict__ bias,
    float* __restrict__ y) {
  __shared__ __align__(16) uint16_t xs[2][XROWS * XPITCH]; // 36,992 B

  const int bid = blockIdx.x;

  // Stagger: desync the co-resident block pair (R6: +8%).
  if (((bid >> 8) ^ bid) & 1) {
    __builtin_amdgcn_s_sleep(127);
    __builtin_amdgcn_s_sleep(127);
  }

  const int f = bid >> 4;   // 0..31
  const int b = bid & 15;   // 0..15

  const int tid = threadIdx.x;
  const int lane = tid & 63;
  const int wco = tid >> 6;    // 0..3 -> co group (32 co each)
  const int l31 = lane & 31;
  const int h = lane >> 5;     // k-half
  const int co0 = wco * 32;

  // ---- W fragments -> registers (once per block) ----
  // chunk c = tap*8 + kc; lane: o = co0+l31, ci = kc*16 + h*8 + j.
  bf16x8 wreg[NWCH];
  if constexpr (PACKED) {
    const uint16_t* wp = wt3 + ((size_t)f * NWCH * CO_ + co0 + l31) * 16 + h * 8;
#pragma unroll
    for (int c = 0; c < NWCH; ++c)
      wreg[c] = *(const bf16x8*)(wp + (size_t)c * WCH_ELEMS);
  } else {
#pragma unroll
    for (int c = 0; c < NWCH; ++c) {
      int tap = c >> 3, ci0 = (c & 7) * 16 + h * 8;
      const float* ws = wraw + (((size_t)(f * CO_ + co0 + l31)) * CI_ + ci0) * K_ + tap;
      union { bf16x8 v; uint16_t hh[8]; } u;
#pragma unroll
      for (int j = 0; j < 8; ++j) u.hh[j] = f2bf(ws[j * K_]);
      wreg[c] = u.v;
    }
  }
  // Bias: lane's D rows are o' = 8g + 4h + r (r=0..3) for reg-quad g.
  float4 bb[4];
#pragma unroll
  for (int g = 0; g < 4; ++g)
    bb[g] = *(const float4*)(bias + f * CO_ + co0 + 8 * g + 4 * h);

  const float* xb = x + ((size_t)b * T_ * F_ + f) * CI_;
  float4 xr[NXV];

  auto load_x = [&](int t0) { // issue global loads for tile window into regs
#pragma unroll
    for (int it = 0; it < NXV; ++it) {
      int idx = tid + it * 256;
      if (idx < XROWS * 32) {
        int row = idx >> 5, c4 = idx & 31;
        int t = t0 - LPAD + row;
        xr[it] = (t >= 0) ? *(const float4*)(xb + (size_t)t * (F_ * CI_) + c4 * 4)
                          : make_float4(0.f, 0.f, 0.f, 0.f);
      }
    }
  };
  auto store_x = [&](uint16_t* dst) { // cvt + write staged regs into LDS buffer
#pragma unroll
    for (int it = 0; it < NXV; ++it) {
      int idx = tid + it * 256;
      if (idx < XROWS * 32) {
        int row = idx >> 5, c4 = idx & 31;
        uint2 pk;
        pk.x = (uint32_t)f2bf(xr[it].x) | ((uint32_t)f2bf(xr[it].y) << 16);
        pk.y = (uint32_t)f2bf(xr[it].z) | ((uint32_t)f2bf(xr[it].w) << 16);
        *(uint2*)&dst[row * XPITCH + c4 * 4] = pk;
      }
    }
  };

  load_x(0);
  store_x(xs[0]);
  load_x(TM); // prefetch tile 1
  __syncthreads(); // prologue: full drain once is fine

  // B-frag base: row = l31 (+2*tap + 32*ts via imm), elem = kc*16 + h*8 (imm).
  const int abase = l31 * XPITCH + h * 8;

#pragma unroll 1
  for (int j = 0; j < 8; ++j) {
    const int t0 = j * TM;
    const uint16_t* xbuf = xs[j & 1];

    f32x16 acc0, acc1;
#pragma unroll
    for (int g = 0; g < 4; ++g) {
      acc0[4 * g + 0] = bb[g].x; acc0[4 * g + 1] = bb[g].y;
      acc0[4 * g + 2] = bb[g].z; acc0[4 * g + 3] = bb[g].w;
      acc1[4 * g + 0] = bb[g].x; acc1[4 * g + 1] = bb[g].y;
      acc1[4 * g + 2] = bb[g].z; acc1[4 * g + 3] = bb[g].w;
    }

#pragma unroll
    for (int c = 0; c < NWCH; ++c) {
      const int tap = c >> 3, kc = c & 7;
      const int off = abase + 2 * tap * XPITCH + kc * 16;
      bf16x8 av0 = *(const bf16x8*)&xbuf[off];                 // ts=0: rows 0..35
      bf16x8 av1 = *(const bf16x8*)&xbuf[off + 32 * XPITCH];   // ts=1: rows 32..67
      acc0 = __builtin_amdgcn_mfma_f32_32x32x16_bf16(wreg[c], av0, acc0, 0, 0, 0);
      acc1 = __builtin_amdgcn_mfma_f32_32x32x16_bf16(wreg[c], av1, acc1, 0, 0, 0);
    }

    // Epilogue: lane stores float4 (4 consecutive co at 8g+4h) per reg-quad,
    // t-row = t0 + 32*ts + l31. Stores stay in flight across counted barrier.
#pragma unroll
    for (int ts = 0; ts < 2; ++ts) {
      float* yb = y + (((size_t)b * T_ + t0 + 32 * ts + l31) * F_ + f) * CO_ + co0 + 4 * h;
      const f32x16& a = ts ? acc1 : acc0;
#pragma unroll
      for (int g = 0; g < 4; ++g) {
        *(float4*)(yb + 8 * g) =
            make_float4(a[4 * g + 0], a[4 * g + 1], a[4 * g + 2], a[4 * g + 3]);
      }
    }

    if (j < 7) {
      store_x(xs[(j + 1) & 1]);        // write NEXT tile into idle buffer
      if (j < 6) load_x((j + 2) * TM); // refill prefetch regs (stay in flight)
      // Counted barrier: only LDS ops must be visible across waves here.
      asm volatile("s_waitcnt lgkmcnt(0)" ::: "memory");
      __builtin_amdgcn_s_barrier();
    }
  }
}

extern "C" void kernel_launch(void* const* d_in, const int* in_sizes, int n_in,
                              void* d_out, int out_size, void* d_ws, size_t ws_size,
                              hipStream_t stream) {
  const float* x = (const float*)d_in[0];
  const float* w = (const float*)d_in[1];
  const float* bias = (const float*)d_in[2];
  float* y = (float*)d_out;

  const size_t wt3_bytes = (size_t)F_ * NWCH * WCH_ELEMS * sizeof(uint16_t); // 3.0 MiB
  const int main_blocks = F_ * B_; // 512 blocks; 2/CU (VGPR-limited 2 waves/SIMD)

  if (ws_size >= wt3_bytes) {
    uint16_t* wt3 = (uint16_t*)d_ws;
    const int total = F_ * CO_ * CI_; // 524288
    repack_w<<<total / 256, 256, 0, stream>>>(w, wt3);
    conv_main<true><<<main_blocks, 256, 0, stream>>>(x, wt3, w, bias, y);
  } else {
    conv_main<false><<<main_blocks, 256, 0, stream>>>(x, (const uint16_t*)nullptr, w, bias, y);
  }
}